// Round 17
// baseline (2062.809 us; speedup 1.0000x reference)
//
#include <hip/hip_runtime.h>

#define NN 262144
#define HH 128
#define EE 16
#define MAXD 12
#define CAP 6144          // per-(depth,category) capacity; expected ~5041 (±70, 15 sigma)
#define CLR 16            // cap: left+right children per slot per depth
#define CH 8              // cap: head children per slot per depth
#define RR 8              // rows per MLP block
#define NB (2 * (CAP / RR))   // loop_k grid: 1536 blocks

typedef float floatx4 __attribute__((ext_vector_type(4)));

struct Prm {
    const float* x_in;
    const int*   parents;
    const int*   depths;
    const int*   states;
    const float* pef;
    const float* plef;
    const float *mW1, *mb1, *mW2, *mb2;
    const float *pW1, *pb1, *pW2, *pb2;
    const float *eW1, *eb1, *eW2, *eb2;
    float* x;
    // zeroed-per-launch:
    int *cntB;            // [36]
    int *cntCLR, *cntCH;  // [12*CAP]
    int *maskL, *maskH;   // [NN] bit d: has left/head child at depth d
    // written by setupA winners:
    int *firstL, *firstH; // [12*NN] canonical list-position ("slot")
    // rebuilt each launch:
    int *listL, *listR, *listHd;   // [12*CAP]
    int *childLR, *childH;         // [12*CAP*CLR], [12*CAP*CH]
    float *stA0, *stA1, *stB0, *stB1;   // [CAP*HH] parity-staged merger/lem outputs
};

// ---------------------------------------------------------------------------
__global__ __launch_bounds__(256)
void copy_x(const floatx4* __restrict__ src, floatx4* __restrict__ dst) {
    int i = blockIdx.x * 256 + threadIdx.x;
    const int gsz = 4096 * 256;
    for (; i < NN * HH / 4; i += gsz) {
        floatx4 v = __builtin_nontemporal_load(&src[i]);
        __builtin_nontemporal_store(v, &dst[i]);
    }
}

// ---------------------------------------------------------------------------
__global__ __launch_bounds__(128)
void setupA(Prm prm) {
    __shared__ int lcnt[36], lbase[36];
    const int tid = threadIdx.x;
    const int gtid = blockIdx.x * 128 + tid;

    if (tid < 36) lcnt[tid] = 0;
    __syncthreads();
    int dep = prm.depths[gtid], st = prm.states[gtid];
    int b = -1, rank = 0, p = 0, winner = 0;
    if (dep >= 1 && (st == 0 || st == 1 || st == 3)) {
        int cat = (st == 3) ? 2 : st;
        b = (dep - 1) * 3 + cat;
        rank = atomicAdd(&lcnt[b], 1);
        p = prm.parents[gtid];
        if (cat == 0) {
            int old = atomicOr(&prm.maskL[p], 1 << dep);
            winner = !((old >> dep) & 1);
        } else if (cat == 2) {
            int old = atomicOr(&prm.maskH[p], 1 << dep);
            winner = !((old >> dep) & 1);
        }
    }
    __syncthreads();
    if (tid < 36 && lcnt[tid] > 0) lbase[tid] = atomicAdd(&prm.cntB[tid], lcnt[tid]);
    __syncthreads();
    if (b >= 0) {
        int idx = lbase[b] + rank;
        if (idx < CAP) {
            int dd = b / 3, cat = b - dd * 3;
            if (cat == 0) {
                prm.listL[dd * CAP + idx] = gtid;
                if (winner) prm.firstL[(size_t)dd * NN + p] = idx;
            } else if (cat == 1) {
                prm.listR[dd * CAP + idx] = gtid;
            } else {
                prm.listHd[dd * CAP + idx] = gtid;
                if (winner) prm.firstH[(size_t)dd * NN + p] = idx;
            }
        }
    }
}

// ---------------------------------------------------------------------------
__global__ __launch_bounds__(256)
void setupC(Prm prm) {
    for (int t = blockIdx.x * 256 + threadIdx.x; t < 12 * CAP; t += gridDim.x * 256) {
        int dd = t / CAP, g = t - dd * CAP;
        int d1 = dd + 1;
        if (g < min(prm.cntB[dd * 3 + 0], CAP)) {
            int c = prm.listL[dd * CAP + g];
            int s = prm.firstL[(size_t)dd * NN + prm.parents[c]];
            int idx = atomicAdd(&prm.cntCLR[dd * CAP + s], 1);
            if (idx < CLR) prm.childLR[(size_t)(dd * CAP + s) * CLR + idx] = c * 2;
        }
        if (g < min(prm.cntB[dd * 3 + 1], CAP)) {
            int c = prm.listR[dd * CAP + g];
            int p = prm.parents[c];
            if ((prm.maskL[p] >> d1) & 1) {
                int s = prm.firstL[(size_t)dd * NN + p];
                int idx = atomicAdd(&prm.cntCLR[dd * CAP + s], 1);
                if (idx < CLR) prm.childLR[(size_t)(dd * CAP + s) * CLR + idx] = c * 2 + 1;
            }
        }
        if (g < min(prm.cntB[dd * 3 + 2], CAP)) {
            int c = prm.listHd[dd * CAP + g];
            int s = prm.firstH[(size_t)dd * NN + prm.parents[c]];
            int idx = atomicAdd(&prm.cntCH[dd * CAP + s], 1);
            if (idx < CH) prm.childH[(size_t)(dd * CAP + s) * CH + idx] = g;
        }
    }
}

// ---------------------------------------------------------------------------
// value of x[i][j] as of AFTER depth dnext=d+1 processing. Nodes updated at
// depth dnext are redirected to its staging (x may not yet hold it); all
// other nodes read x directly (complete through dnext+1 by induction).
__device__ __forceinline__
float resolve1(const Prm& prm, const float* __restrict__ stA_r,
               const float* __restrict__ stB_r, int dnext, int i, int j) {
    int bit = 1 << dnext;                 // dnext=13 -> bit never set in masks
    if (prm.maskL[i] & bit)
        return stA_r[(size_t)prm.firstL[(size_t)(dnext - 1) * NN + i] * HH + j];
    if (prm.maskH[i] & bit)
        return stB_r[(size_t)prm.firstH[(size_t)(dnext - 1) * NN + i] * HH + j];
    return prm.x[(size_t)i * HH + j];
}

// ---------------------------------------------------------------------------
// apply staged outputs of depth dap into x (canonical rows only; merger
// priority over lem). Writers touch exactly the rows resolve1 redirects, so
// concurrent readers never see partial state.
__device__ __forceinline__
void apply_stage(const Prm& prm, const float* __restrict__ stA_r,
                 const float* __restrict__ stB_r, int dap, int bid, int nblocks) {
    int dd = dap - 1;
    int nL = min(prm.cntB[dd * 3 + 0], CAP);
    int nH = min(prm.cntB[dd * 3 + 2], CAP);
    int h = threadIdx.x >> 7, j = threadIdx.x & 127;
    int total = nL + nH;
    for (int g = bid * 2 + h; g < total; g += nblocks * 2) {
        if (g < nL) {
            int p = prm.parents[prm.listL[dd * CAP + g]];
            if (g == prm.firstL[(size_t)dd * NN + p])
                prm.x[(size_t)p * HH + j] = stA_r[(size_t)g * HH + j];
        } else {
            int g2 = g - nL;
            int p = prm.parents[prm.listHd[dd * CAP + g2]];
            if (g2 == prm.firstH[(size_t)dd * NN + p] && !((prm.maskL[p] >> dap) & 1))
                prm.x[(size_t)p * HH + j] = stB_r[(size_t)g2 * HH + j];
        }
    }
}

// ---------------------------------------------------------------------------
// batched RR-row split-K 2-layer MLP (R13/R14-proven). Caller staged sh_in.
// outv[r] valid for h==0 threads on return.
template <int INDIM>
__device__ __forceinline__
void mlp_batch(int h, int j,
               const float* __restrict__ W1, const float* __restrict__ b1,
               const float* __restrict__ W2, const float* __restrict__ b2,
               float (*sh_in)[INDIM], float (*sh_h)[HH], float (*sh_pt)[HH],
               float* outv) {
    constexpr int KH1 = INDIM / 2;
    float acc[RR];
    #pragma unroll
    for (int r = 0; r < RR; ++r) acc[r] = 0.f;
    {
        const float* Wp = W1 + (size_t)h * KH1 * HH + j;
        for (int k = 0; k < KH1; k += 8) {
            float wv[8];
            #pragma unroll
            for (int u = 0; u < 8; ++u) wv[u] = Wp[(size_t)(k + u) * HH];
            #pragma unroll
            for (int u = 0; u < 8; ++u) {
                float w = wv[u];
                int kk = h * KH1 + k + u;
                #pragma unroll
                for (int r = 0; r < RR; ++r) acc[r] += sh_in[r][kk] * w;
            }
        }
    }
    if (h == 1) {
        #pragma unroll
        for (int r = 0; r < RR; ++r) sh_pt[r][j] = acc[r];
    }
    __syncthreads();
    if (h == 0) {
        float bb = b1[j];
        #pragma unroll
        for (int r = 0; r < RR; ++r) sh_h[r][j] = fmaxf(acc[r] + sh_pt[r][j] + bb, 0.f);
    }
    __syncthreads();
    float acc2[RR];
    #pragma unroll
    for (int r = 0; r < RR; ++r) acc2[r] = 0.f;
    {
        const float* Wp = W2 + (size_t)h * (HH / 2) * HH + j;
        for (int k = 0; k < HH / 2; k += 8) {
            float wv[8];
            #pragma unroll
            for (int u = 0; u < 8; ++u) wv[u] = Wp[(size_t)(k + u) * HH];
            #pragma unroll
            for (int u = 0; u < 8; ++u) {
                float w = wv[u];
                int kk = h * (HH / 2) + k + u;
                #pragma unroll
                for (int r = 0; r < RR; ++r) acc2[r] += sh_h[r][kk] * w;
            }
        }
    }
    if (h == 1) {
        #pragma unroll
        for (int r = 0; r < RR; ++r) sh_pt[r][j] = acc2[r];
    }
    __syncthreads();
    if (h == 0) {
        float bb2 = b2[j];
        #pragma unroll
        for (int r = 0; r < RR; ++r) outv[r] = acc2[r] + sh_pt[r][j] + bb2;
    }
    __syncthreads();
}

// ---------------------------------------------------------------------------
// ONE dispatch per depth. All blocks first apply depth-(d+1) staging to x,
// then: blocks [0,CAP/RR) = merger (inline gather) -> stA[d&1];
//       blocks [CAP/RR,NB) = head (inline batched lep + lem) -> stB[d&1].
// All x reads go through resolve1 (depth-(d+1) redirection).
__global__ __launch_bounds__(256, 4)
void loop_k(Prm prm, int d) {
    const int dd = d - 1;
    const int tid = threadIdx.x, h = tid >> 7, j = tid & 127;
    const int bid = blockIdx.x;

    const float* stA_r = ((d + 1) & 1) ? prm.stA1 : prm.stA0;
    const float* stB_r = ((d + 1) & 1) ? prm.stB1 : prm.stB0;
    float* stA_w = (d & 1) ? prm.stA1 : prm.stA0;
    float* stB_w = (d & 1) ? prm.stB1 : prm.stB0;

    if (d < MAXD) apply_stage(prm, stA_r, stB_r, d + 1, bid, NB);

    __shared__ float shr[RR * (2 * HH + EE) + 2 * RR * HH + RR * HH];
    __shared__ int pArr[RR];
    __shared__ char canA[RR];

    if (bid < CAP / RR) {
        // ---------------- merger block: inline gather + MLP -> stA_w ------
        int nL = min(prm.cntB[dd * 3 + 0], CAP);
        int g0 = bid * RR;
        if (g0 >= nL) return;
        float (*sh_in)[2 * HH + EE] = (float (*)[2 * HH + EE])shr;
        float (*sh_h)[HH]  = (float (*)[HH])(shr + RR * (2 * HH + EE));
        float (*sh_pt)[HH] = (float (*)[HH])(shr + RR * (2 * HH + EE) + RR * HH);

        if (tid < RR) {
            int g = g0 + tid; int p = -1; char cn = 0;
            if (g < nL) {
                p = prm.parents[prm.listL[dd * CAP + g]];
                cn = (g == prm.firstL[(size_t)dd * NN + p]);
            }
            pArr[tid] = p; canA[tid] = cn;
        }
        __syncthreads();
        #pragma unroll
        for (int i = 0; i < RR / 2; ++i) {
            int r = h + 2 * i; int g = g0 + r;
            float lv = 0.f, rv = 0.f;
            bool act = (g < nL) && canA[r];
            if (act) {
                int cb = dd * CAP + g;
                int cnt = min(prm.cntCLR[cb], CLR);
                for (int k = 0; k < cnt; ++k) {
                    int e = prm.childLR[(size_t)cb * CLR + k];
                    float v = resolve1(prm, stA_r, stB_r, d + 1, e >> 1, j);
                    if (e & 1) rv += v; else lv += v;
                }
            }
            sh_in[r][j] = lv;
            sh_in[r][HH + j] = rv;
            if (j < EE) sh_in[r][2 * HH + j] = act ? prm.pef[(size_t)pArr[r] * EE + j] : 0.f;
        }
        __syncthreads();
        float outv[RR];
        mlp_batch<2 * HH + EE>(h, j, prm.mW1, prm.mb1, prm.mW2, prm.mb2,
                               sh_in, sh_h, sh_pt, outv);
        if (h == 0) {
            #pragma unroll
            for (int r = 0; r < RR; ++r) {
                int g = g0 + r;
                if (g < nL && canA[r])
                    stA_w[(size_t)g * HH + j] = outv[r];
            }
        }
    } else {
        // ---------------- head block: inline lep (batched) + lem -> stB_w -
        int nH = min(prm.cntB[dd * 3 + 2], CAP);
        int g0 = (bid - CAP / RR) * RR;
        if (g0 >= nH) return;
        float (*sh_in)[2 * HH] = (float (*)[2 * HH])shr;
        float (*sh_li)[HH + EE] = (float (*)[HH + EE])shr;
        float (*sh_h)[HH]  = (float (*)[HH])(shr + RR * 2 * HH);
        float (*sh_pt)[HH] = (float (*)[HH])(shr + RR * 2 * HH + RR * HH);
        float (*mh)[HH]    = (float (*)[HH])(shr + RR * 2 * HH + 2 * RR * HH);
        __shared__ int chN;
        __shared__ short chPos[RR * CH];
        __shared__ char  chRow[RR * CH];

        if (tid == 0) chN = 0;
        __syncthreads();
        if (tid < RR) {
            int g = g0 + tid; int p = -1; char cn = 0;
            if (g < nH) {
                p = prm.parents[prm.listHd[dd * CAP + g]];
                cn = (g == prm.firstH[(size_t)dd * NN + p]);
            }
            pArr[tid] = p; canA[tid] = cn;
            if (cn) {
                int cb = dd * CAP + g;
                int cnt = min(prm.cntCH[cb], CH);
                int base = atomicAdd(&chN, cnt);
                for (int k = 0; k < cnt; ++k) {
                    chPos[base + k] = (short)prm.childH[(size_t)cb * CH + k];
                    chRow[base + k] = (char)tid;
                }
            }
        }
        for (int q = tid; q < RR * HH; q += 256) ((float*)mh)[q] = 0.f;
        __syncthreads();

        int total = chN;
        for (int c0 = 0; c0 < total; c0 += RR) {
            for (int idx = tid; idx < RR * (HH + EE); idx += 256) {
                int e = idx / (HH + EE), k = idx - e * (HH + EE);
                float v = 0.f;
                if (c0 + e < total) {
                    int ci = prm.listHd[dd * CAP + chPos[c0 + e]];
                    v = (k < HH) ? resolve1(prm, stA_r, stB_r, d + 1, ci, k)
                                 : prm.plef[(size_t)ci * EE + (k - HH)];
                }
                sh_li[e][k] = v;
            }
            __syncthreads();
            float outv[RR];
            mlp_batch<HH + EE>(h, j, prm.pW1, prm.pb1, prm.pW2, prm.pb2,
                               sh_li, sh_h, sh_pt, outv);
            if (h == 0) {
                #pragma unroll
                for (int e = 0; e < RR; ++e)
                    if (c0 + e < total) mh[chRow[c0 + e]][j] += outv[e];
            }
            __syncthreads();
        }

        #pragma unroll
        for (int i = 0; i < RR / 2; ++i) {
            int r = h + 2 * i; int g = g0 + r;
            bool act = (g < nH) && canA[r];
            sh_in[r][j] = act ? resolve1(prm, stA_r, stB_r, d + 1, pArr[r], j) : 0.f;
            sh_in[r][HH + j] = act ? mh[r][j] : 0.f;
        }
        __syncthreads();
        float outv[RR];
        mlp_batch<2 * HH>(h, j, prm.eW1, prm.eb1, prm.eW2, prm.eb2,
                          sh_in, sh_h, sh_pt, outv);
        if (h == 0) {
            #pragma unroll
            for (int r = 0; r < RR; ++r) {
                int g = g0 + r;
                if (g < nH && canA[r])
                    stB_w[(size_t)g * HH + j] = outv[r];
            }
        }
    }
}

// ---------------------------------------------------------------------------
// apply depth-1 staging (parity 1) into x
__global__ __launch_bounds__(256)
void finalize(Prm prm) {
    apply_stage(prm, prm.stA1, prm.stB1, 1, blockIdx.x, gridDim.x);
}

// ---------------------------------------------------------------------------
extern "C" void kernel_launch(void* const* d_in, const int* in_sizes, int n_in,
                              void* d_out, int out_size, void* d_ws, size_t ws_size,
                              hipStream_t stream) {
    Prm prm;
    prm.x_in    = (const float*)d_in[0];
    const int* edge = (const int*)d_in[1];
    prm.depths  = (const int*)d_in[2];
    prm.states  = (const int*)d_in[3];
    prm.pef     = (const float*)d_in[4];
    prm.plef    = (const float*)d_in[5];
    prm.mW1 = (const float*)d_in[6];  prm.mb1 = (const float*)d_in[7];
    prm.mW2 = (const float*)d_in[8];  prm.mb2 = (const float*)d_in[9];
    prm.pW1 = (const float*)d_in[10]; prm.pb1 = (const float*)d_in[11];
    prm.pW2 = (const float*)d_in[12]; prm.pb2 = (const float*)d_in[13];
    prm.eW1 = (const float*)d_in[14]; prm.eb1 = (const float*)d_in[15];
    prm.eW2 = (const float*)d_in[16]; prm.eb2 = (const float*)d_in[17];
    prm.x = (float*)d_out;
    prm.parents = edge + NN;

    char* w = (char*)d_ws;
    auto alloc = [&](size_t bytes) {
        void* p = (void*)w;
        w += (bytes + 255) & ~(size_t)255;
        return p;
    };
    // ---- zeroed region ----
    char* zbase = w;
    prm.cntB   = (int*)alloc(64 * 4);
    prm.cntCLR = (int*)alloc((size_t)12 * CAP * 4);
    prm.cntCH  = (int*)alloc((size_t)12 * CAP * 4);
    prm.maskL  = (int*)alloc((size_t)NN * 4);
    prm.maskH  = (int*)alloc((size_t)NN * 4);
    size_t zbytes = (size_t)(w - zbase);
    // ---- written by setupA winners (no init needed) ----
    prm.firstL = (int*)alloc((size_t)12 * NN * 4);
    prm.firstH = (int*)alloc((size_t)12 * NN * 4);
    // ---- rebuilt each launch ----
    prm.listL   = (int*)alloc((size_t)12 * CAP * 4);
    prm.listR   = (int*)alloc((size_t)12 * CAP * 4);
    prm.listHd  = (int*)alloc((size_t)12 * CAP * 4);
    prm.childLR = (int*)alloc((size_t)12 * CAP * CLR * 4);
    prm.childH  = (int*)alloc((size_t)12 * CAP * CH * 4);
    prm.stA0    = (float*)alloc((size_t)CAP * HH * 4);
    prm.stA1    = (float*)alloc((size_t)CAP * HH * 4);
    prm.stB0    = (float*)alloc((size_t)CAP * HH * 4);
    prm.stB1    = (float*)alloc((size_t)CAP * HH * 4);

    hipMemsetAsync(zbase, 0, zbytes, stream);

    copy_x<<<4096, 256, 0, stream>>>((const floatx4*)prm.x_in, (floatx4*)prm.x);
    setupA<<<NN / 128, 128, 0, stream>>>(prm);
    setupC<<<384, 256, 0, stream>>>(prm);

    for (int d = MAXD; d >= 1; --d)
        loop_k<<<NB, 256, 0, stream>>>(prm, d);

    finalize<<<1024, 256, 0, stream>>>(prm);
}

// Round 18
// 784.893 us; speedup vs baseline: 2.6281x; 2.6281x over previous
//
#include <hip/hip_runtime.h>

#define NN 262144
#define HH 128
#define EE 16
#define MAXD 12
#define CAP 6144          // per-(depth,category) capacity; expected ~5041 (±70, 15 sigma)
#define CLR 16            // cap: left+right children per slot per depth
#define CH 8              // cap: head children per slot per depth
#define RR 8              // rows per MLP block
#define G_GATHER 320      // S1: blocks [0,G_GATHER) gather (8 workers each), rest lep MLP

typedef float floatx4 __attribute__((ext_vector_type(4)));   // native vec for nontemporal builtins

struct Prm {
    const float* x_in;
    const int*   parents;
    const int*   depths;
    const int*   states;
    const float* pef;
    const float* plef;
    const float *mW1, *mb1, *mW2, *mb2;
    const float *pW1, *pb1, *pW2, *pb2;
    const float *eW1, *eb1, *eW2, *eb2;
    float* x;
    // zeroed-per-launch:
    int *cntB;            // [36]
    int *cntCLR, *cntCH;  // [12*CAP] each
    int *maskL, *maskH;   // [NN] bit d: has left/head child at depth d (also winner-tracker)
    // written by winner in setupA (only read for parents that have children):
    int *firstL, *firstH; // [12*NN] canonical list-position ("slot")
    // rebuilt each launch before use:
    int *listL, *listR, *listHd;       // [12*CAP]
    int *childLR, *childH;             // [12*CAP*CLR], [12*CAP*CH]
    float *left_c, *right_c, *lepOut;  // [CAP*HH]
};

// ---------------------------------------------------------------------------
// x copy through the COMPUTE path (L2-coherent; SDMA memcpy caused R9's stale-
// line failure). Nontemporal: pure streaming, don't pollute L2.
__global__ __launch_bounds__(256)
void copy_x(const floatx4* __restrict__ src, floatx4* __restrict__ dst) {
    int i = blockIdx.x * 256 + threadIdx.x;
    const int gsz = 4096 * 256;
    for (; i < NN * HH / 4; i += gsz) {
        floatx4 v = __builtin_nontemporal_load(&src[i]);
        __builtin_nontemporal_store(v, &dst[i]);
    }
}

// ---------------------------------------------------------------------------
// setup A: bucket nodes by (depth, cat), masks, winner-based slot assignment
__global__ __launch_bounds__(128)
void setupA(Prm prm) {
    __shared__ int lcnt[36], lbase[36];
    const int tid = threadIdx.x;
    const int gtid = blockIdx.x * 128 + tid;       // node id (2048*128 = NN)

    if (tid < 36) lcnt[tid] = 0;
    __syncthreads();
    int dep = prm.depths[gtid], st = prm.states[gtid];
    int b = -1, rank = 0, p = 0, winner = 0;
    if (dep >= 1 && (st == 0 || st == 1 || st == 3)) {
        int cat = (st == 3) ? 2 : st;
        b = (dep - 1) * 3 + cat;
        rank = atomicAdd(&lcnt[b], 1);
        p = prm.parents[gtid];
        if (cat == 0) {
            int old = atomicOr(&prm.maskL[p], 1 << dep);
            winner = !((old >> dep) & 1);
        } else if (cat == 2) {
            int old = atomicOr(&prm.maskH[p], 1 << dep);
            winner = !((old >> dep) & 1);
        }
    }
    __syncthreads();
    if (tid < 36 && lcnt[tid] > 0) lbase[tid] = atomicAdd(&prm.cntB[tid], lcnt[tid]);
    __syncthreads();
    if (b >= 0) {
        int idx = lbase[b] + rank;
        if (idx < CAP) {
            int dd = b / 3, cat = b - dd * 3;
            if (cat == 0) {
                prm.listL[dd * CAP + idx] = gtid;
                if (winner) prm.firstL[(size_t)dd * NN + p] = idx;
            } else if (cat == 1) {
                prm.listR[dd * CAP + idx] = gtid;
            } else {
                prm.listHd[dd * CAP + idx] = gtid;
                if (winner) prm.firstH[(size_t)dd * NN + p] = idx;
            }
        }
    }
}

// ---------------------------------------------------------------------------
// setup C: append children to per-slot lists (scattered atomics only)
__global__ __launch_bounds__(256)
void setupC(Prm prm) {
    for (int t = blockIdx.x * 256 + threadIdx.x; t < 12 * CAP; t += gridDim.x * 256) {
        int dd = t / CAP, g = t - dd * CAP;
        int d1 = dd + 1;
        if (g < min(prm.cntB[dd * 3 + 0], CAP)) {            // lefts (tag 0)
            int c = prm.listL[dd * CAP + g];
            int s = prm.firstL[(size_t)dd * NN + prm.parents[c]];
            int idx = atomicAdd(&prm.cntCLR[dd * CAP + s], 1);
            if (idx < CLR) prm.childLR[(size_t)(dd * CAP + s) * CLR + idx] = c * 2;
        }
        if (g < min(prm.cntB[dd * 3 + 1], CAP)) {            // rights (tag 1)
            int c = prm.listR[dd * CAP + g];
            int p = prm.parents[c];
            if ((prm.maskL[p] >> d1) & 1) {                  // only if parent has a left
                int s = prm.firstL[(size_t)dd * NN + p];
                int idx = atomicAdd(&prm.cntCLR[dd * CAP + s], 1);
                if (idx < CLR) prm.childLR[(size_t)(dd * CAP + s) * CLR + idx] = c * 2 + 1;
            }
        }
        if (g < min(prm.cntB[dd * 3 + 2], CAP)) {            // heads: store POSITION g
            int c = prm.listHd[dd * CAP + g];
            int s = prm.firstH[(size_t)dd * NN + prm.parents[c]];
            int idx = atomicAdd(&prm.cntCH[dd * CAP + s], 1);
            if (idx < CH) prm.childH[(size_t)(dd * CAP + s) * CH + idx] = g;
        }
    }
}

// ---------------------------------------------------------------------------
// RR-row 2-layer MLP, 256 threads, split-K halves h=tid>>7, batch-8 weight
// preload + FLOAT4 LDS reads (b128: 4x fewer LDS wave-ops than b32 scalar).
// Alignment: KH1 in {136,72,64} all multiples of 8 -> 16B-aligned offsets.
template <int MODE, int INDIM>
__device__ void mlpR(const Prm& prm, int d, int g0, int n,
                     const int* __restrict__ rowList,
                     const float* __restrict__ W1, const float* __restrict__ b1,
                     const float* __restrict__ W2, const float* __restrict__ b2,
                     float* sh_raw) {
    const int tid = threadIdx.x;
    const int h = tid >> 7, j = tid & 127;
    float (*sh_in)[INDIM] = (float (*)[INDIM])sh_raw;
    float (*sh_h)[HH]     = (float (*)[HH])(sh_raw + RR * INDIM);
    float (*sh_pt)[HH]    = (float (*)[HH])(sh_raw + RR * INDIM + RR * HH);
    const int dd = d - 1;

    if (MODE == 0) {
        #pragma unroll
        for (int i = 0; i < RR / 2; ++i) {
            int r = h + 2 * i;                      // each half stages 4 rows
            int g = g0 + r;
            float lv = 0.f, rv = 0.f, pv = 0.f;
            if (g < n) {
                int p = prm.parents[rowList[g]];
                int s = prm.firstL[(size_t)dd * NN + p];
                lv = prm.left_c [(size_t)s * HH + j];
                rv = prm.right_c[(size_t)s * HH + j];
                if (j < EE) pv = prm.pef[(size_t)p * EE + j];
            }
            sh_in[r][j] = lv;
            sh_in[r][HH + j] = rv;
            if (j < EE) sh_in[r][2 * HH + j] = pv;
        }
    } else if (MODE == 2) {
        #pragma unroll
        for (int i = 0; i < RR / 2; ++i) {
            int r = h + 2 * i;
            int g = g0 + r;
            float xv = 0.f, mh = 0.f;
            if (g < n) {
                int p = prm.parents[rowList[g]];
                int s = prm.firstH[(size_t)dd * NN + p];
                xv = prm.x[(size_t)p * HH + j];
                int cb = dd * CAP + s;
                int cnt = prm.cntCH[cb];
                if (cnt > CH) cnt = CH;
                for (int i2 = 0; i2 < cnt; ++i2) {
                    int pos = prm.childH[(size_t)cb * CH + i2];
                    mh += prm.lepOut[(size_t)pos * HH + j];
                }
            }
            sh_in[r][j] = xv;
            sh_in[r][HH + j] = mh;
        }
    } else {
        for (int idx = tid; idx < RR * INDIM; idx += 256) {
            int r = idx / INDIM, k = idx - r * INDIM;
            int g = g0 + r;
            float v = 0.f;
            if (g < n) {
                int c = rowList[g];
                if (k < HH) v = prm.x[(size_t)c * HH + k];
                else        v = prm.plef[(size_t)c * EE + (k - HH)];
            }
            sh_in[r][k] = v;
        }
    }
    __syncthreads();

    constexpr int KH1 = INDIM / 2;
    const int kbase = h * KH1;
    float acc[RR];
    #pragma unroll
    for (int r = 0; r < RR; ++r) acc[r] = 0.f;
    {
        const float* Wp = W1 + (size_t)h * KH1 * HH + j;
        for (int k = 0; k < KH1; k += 8) {
            float wv[8];
            #pragma unroll
            for (int u = 0; u < 8; ++u) wv[u] = Wp[(size_t)(k + u) * HH];
            #pragma unroll
            for (int r = 0; r < RR; ++r) {
                float4 a0 = *(const float4*)&sh_in[r][kbase + k];
                float4 a1 = *(const float4*)&sh_in[r][kbase + k + 4];
                acc[r] += a0.x * wv[0] + a0.y * wv[1] + a0.z * wv[2] + a0.w * wv[3]
                        + a1.x * wv[4] + a1.y * wv[5] + a1.z * wv[6] + a1.w * wv[7];
            }
        }
    }
    if (h == 1) {
        #pragma unroll
        for (int r = 0; r < RR; ++r) sh_pt[r][j] = acc[r];
    }
    __syncthreads();
    if (h == 0) {
        float bb = b1[j];
        #pragma unroll
        for (int r = 0; r < RR; ++r) sh_h[r][j] = fmaxf(acc[r] + sh_pt[r][j] + bb, 0.f);
    }
    __syncthreads();

    float acc2[RR];
    #pragma unroll
    for (int r = 0; r < RR; ++r) acc2[r] = 0.f;
    {
        const float* Wp = W2 + (size_t)h * (HH / 2) * HH + j;
        const int kb2 = h * (HH / 2);
        for (int k = 0; k < HH / 2; k += 8) {
            float wv[8];
            #pragma unroll
            for (int u = 0; u < 8; ++u) wv[u] = Wp[(size_t)(k + u) * HH];
            #pragma unroll
            for (int r = 0; r < RR; ++r) {
                float4 a0 = *(const float4*)&sh_h[r][kb2 + k];
                float4 a1 = *(const float4*)&sh_h[r][kb2 + k + 4];
                acc2[r] += a0.x * wv[0] + a0.y * wv[1] + a0.z * wv[2] + a0.w * wv[3]
                         + a1.x * wv[4] + a1.y * wv[5] + a1.z * wv[6] + a1.w * wv[7];
            }
        }
    }
    if (h == 1) {
        #pragma unroll
        for (int r = 0; r < RR; ++r) sh_pt[r][j] = acc2[r];
    }
    __syncthreads();
    if (h == 0) {
        float bb2 = b2[j];
        for (int r = 0; r < RR; ++r) {
            int g = g0 + r;
            if (g >= n) break;
            float val = acc2[r] + sh_pt[r][j] + bb2;
            if (MODE == 1) {
                prm.lepOut[(size_t)g * HH + j] = val;
            } else if (MODE == 0) {
                int p = prm.parents[rowList[g]];
                if (g == prm.firstL[(size_t)dd * NN + p])      // canonical dup only
                    prm.x[(size_t)p * HH + j] = val;
            } else {
                int p = prm.parents[rowList[g]];
                if (g == prm.firstH[(size_t)dd * NN + p] &&    // canonical dup only
                    !((prm.maskL[p] >> d) & 1))                // parents_mask priority
                    prm.x[(size_t)p * HH + j] = val;
            }
        }
    }
}

// ---------------------------------------------------------------------------
// S1 (reads x only): gather left/right child sums [0,G_GATHER) || lep MLP rest
__global__ __launch_bounds__(256, 4)
void s1_kernel(Prm prm, int d) {
    const int dd = d - 1;
    const int bid = blockIdx.x, tid = threadIdx.x;
    if (bid < G_GATHER) {
        int nL = min(prm.cntB[dd * 3 + 0], CAP);
        int w = tid >> 5, lane = tid & 31;          // 8 workers x 32 lanes, float4
        for (int s = bid * 8 + w; s < nL; s += G_GATHER * 8) {
            int cb = dd * CAP + s;
            int cnt = prm.cntCLR[cb];
            if (cnt > CLR) cnt = CLR;
            float4 l = make_float4(0.f, 0.f, 0.f, 0.f);
            float4 rt = make_float4(0.f, 0.f, 0.f, 0.f);
            for (int i = 0; i < cnt; ++i) {
                int e = prm.childLR[(size_t)cb * CLR + i];
                const float4 v = *(const float4*)(prm.x + (size_t)(e >> 1) * HH + lane * 4);
                if (e & 1) { rt.x += v.x; rt.y += v.y; rt.z += v.z; rt.w += v.w; }
                else       { l.x  += v.x; l.y  += v.y; l.z  += v.z; l.w  += v.w; }
            }
            *(float4*)(prm.left_c  + (size_t)s * HH + lane * 4) = l;
            *(float4*)(prm.right_c + (size_t)s * HH + lane * 4) = rt;
        }
    } else {
        __shared__ float sh_raw[RR * (HH + EE) + 2 * RR * HH];
        int nH = min(prm.cntB[dd * 3 + 2], CAP);
        int g0 = (bid - G_GATHER) * RR;
        if (g0 < nH)
            mlpR<1, HH + EE>(prm, d, g0, nH, prm.listHd + dd * CAP,
                             prm.pW1, prm.pb1, prm.pW2, prm.pb2, sh_raw);
    }
}

// ---------------------------------------------------------------------------
// S2 (writes x): merger [0,CAP/RR) || lem [CAP/RR, 2*CAP/RR).
__global__ __launch_bounds__(256, 4)
void s2_kernel(Prm prm, int d) {
    const int dd = d - 1;
    const int bid = blockIdx.x;
    __shared__ float sh_raw[RR * (2 * HH + EE) + 2 * RR * HH];
    if (bid < CAP / RR) {
        int nL = min(prm.cntB[dd * 3 + 0], CAP);
        int g0 = bid * RR;
        if (g0 < nL)
            mlpR<0, 2 * HH + EE>(prm, d, g0, nL, prm.listL + dd * CAP,
                                 prm.mW1, prm.mb1, prm.mW2, prm.mb2, sh_raw);
    } else {
        int nH = min(prm.cntB[dd * 3 + 2], CAP);
        int g0 = (bid - CAP / RR) * RR;
        if (g0 < nH)
            mlpR<2, 2 * HH>(prm, d, g0, nH, prm.listHd + dd * CAP,
                            prm.eW1, prm.eb1, prm.eW2, prm.eb2, sh_raw);
    }
}

// ---------------------------------------------------------------------------
extern "C" void kernel_launch(void* const* d_in, const int* in_sizes, int n_in,
                              void* d_out, int out_size, void* d_ws, size_t ws_size,
                              hipStream_t stream) {
    Prm prm;
    prm.x_in    = (const float*)d_in[0];
    const int* edge = (const int*)d_in[1];
    prm.depths  = (const int*)d_in[2];
    prm.states  = (const int*)d_in[3];
    prm.pef     = (const float*)d_in[4];
    prm.plef    = (const float*)d_in[5];
    prm.mW1 = (const float*)d_in[6];  prm.mb1 = (const float*)d_in[7];
    prm.mW2 = (const float*)d_in[8];  prm.mb2 = (const float*)d_in[9];
    prm.pW1 = (const float*)d_in[10]; prm.pb1 = (const float*)d_in[11];
    prm.pW2 = (const float*)d_in[12]; prm.pb2 = (const float*)d_in[13];
    prm.eW1 = (const float*)d_in[14]; prm.eb1 = (const float*)d_in[15];
    prm.eW2 = (const float*)d_in[16]; prm.eb2 = (const float*)d_in[17];
    prm.x = (float*)d_out;
    prm.parents = edge + NN;

    char* w = (char*)d_ws;
    auto alloc = [&](size_t bytes) {
        void* p = (void*)w;
        w += (bytes + 255) & ~(size_t)255;
        return p;
    };
    // ---- zeroed region ----
    char* zbase = w;
    prm.cntB   = (int*)alloc(64 * 4);
    prm.cntCLR = (int*)alloc((size_t)12 * CAP * 4);
    prm.cntCH  = (int*)alloc((size_t)12 * CAP * 4);
    prm.maskL  = (int*)alloc((size_t)NN * 4);
    prm.maskH  = (int*)alloc((size_t)NN * 4);
    size_t zbytes = (size_t)(w - zbase);
    // ---- written by setupA winners (no init needed) ----
    prm.firstL = (int*)alloc((size_t)12 * NN * 4);
    prm.firstH = (int*)alloc((size_t)12 * NN * 4);
    // ---- non-zeroed (fully rebuilt before use each launch) ----
    prm.listL     = (int*)alloc((size_t)12 * CAP * 4);
    prm.listR     = (int*)alloc((size_t)12 * CAP * 4);
    prm.listHd    = (int*)alloc((size_t)12 * CAP * 4);
    prm.childLR   = (int*)alloc((size_t)12 * CAP * CLR * 4);
    prm.childH    = (int*)alloc((size_t)12 * CAP * CH * 4);
    prm.left_c    = (float*)alloc((size_t)CAP * HH * 4);
    prm.right_c   = (float*)alloc((size_t)CAP * HH * 4);
    prm.lepOut    = (float*)alloc((size_t)CAP * HH * 4);

    hipMemsetAsync(zbase, 0, zbytes, stream);

    copy_x<<<4096, 256, 0, stream>>>((const floatx4*)prm.x_in, (floatx4*)prm.x);
    setupA<<<NN / 128, 128, 0, stream>>>(prm);
    setupC<<<384, 256, 0, stream>>>(prm);

    for (int d = MAXD; d >= 1; --d) {
        s1_kernel<<<G_GATHER + CAP / RR, 256, 0, stream>>>(prm, d);
        s2_kernel<<<2 * (CAP / RR), 256, 0, stream>>>(prm, d);
    }
}

// Round 19
// 733.924 us; speedup vs baseline: 2.8107x; 1.0694x over previous
//
#include <hip/hip_runtime.h>

#define NN 262144
#define HH 128
#define EE 16
#define MAXD 12
#define CAP 6144          // per-(depth,category) capacity; expected ~5041 (±70, 15 sigma)
#define CLR 16            // cap: left+right children per slot per depth
#define CH 8              // cap: head children per slot per depth
#define RR 8              // rows per MLP block
#define G_GATHER 320      // S1: blocks [0,G_GATHER) gather (8 workers each), rest lep MLP

typedef float floatx4 __attribute__((ext_vector_type(4)));   // native vec for nontemporal builtins

struct Prm {
    const float* x_in;
    const int*   parents;
    const int*   depths;
    const int*   states;
    const float* pef;
    const float* plef;
    const float *mW1, *mb1, *mW2, *mb2;
    const float *pW1, *pb1, *pW2, *pb2;
    const float *eW1, *eb1, *eW2, *eb2;
    float* x;
    // zeroed-per-launch:
    int *cntB;            // [36]
    int *cntCLR, *cntCH;  // [12*CAP] each
    int *maskL, *maskH;   // [NN] bit d: has left/head child at depth d (also winner-tracker)
    // written by winner in setupA (only read for parents that have children):
    int *firstL, *firstH; // [12*NN] canonical list-position ("slot")
    // rebuilt each launch before use:
    int *listL, *listR, *listHd;       // [12*CAP]
    int *childLR, *childH;             // [12*CAP*CLR], [12*CAP*CH]
    float *left_c, *right_c, *lepOut;  // [CAP*HH]
};

// ---------------------------------------------------------------------------
// x copy through the COMPUTE path (L2-coherent; SDMA memcpy caused R9's stale-
// line failure). Nontemporal: pure streaming, don't pollute L2.
__global__ __launch_bounds__(256)
void copy_x(const floatx4* __restrict__ src, floatx4* __restrict__ dst) {
    int i = blockIdx.x * 256 + threadIdx.x;
    const int gsz = 4096 * 256;
    for (; i < NN * HH / 4; i += gsz) {
        floatx4 v = __builtin_nontemporal_load(&src[i]);
        __builtin_nontemporal_store(v, &dst[i]);
    }
}

// ---------------------------------------------------------------------------
// setup A: bucket nodes by (depth, cat), masks, winner-based slot assignment
__global__ __launch_bounds__(128)
void setupA(Prm prm) {
    __shared__ int lcnt[36], lbase[36];
    const int tid = threadIdx.x;
    const int gtid = blockIdx.x * 128 + tid;       // node id (2048*128 = NN)

    if (tid < 36) lcnt[tid] = 0;
    __syncthreads();
    int dep = prm.depths[gtid], st = prm.states[gtid];
    int b = -1, rank = 0, p = 0, winner = 0;
    if (dep >= 1 && (st == 0 || st == 1 || st == 3)) {
        int cat = (st == 3) ? 2 : st;
        b = (dep - 1) * 3 + cat;
        rank = atomicAdd(&lcnt[b], 1);
        p = prm.parents[gtid];
        if (cat == 0) {
            int old = atomicOr(&prm.maskL[p], 1 << dep);
            winner = !((old >> dep) & 1);
        } else if (cat == 2) {
            int old = atomicOr(&prm.maskH[p], 1 << dep);
            winner = !((old >> dep) & 1);
        }
    }
    __syncthreads();
    if (tid < 36 && lcnt[tid] > 0) lbase[tid] = atomicAdd(&prm.cntB[tid], lcnt[tid]);
    __syncthreads();
    if (b >= 0) {
        int idx = lbase[b] + rank;
        if (idx < CAP) {
            int dd = b / 3, cat = b - dd * 3;
            if (cat == 0) {
                prm.listL[dd * CAP + idx] = gtid;
                if (winner) prm.firstL[(size_t)dd * NN + p] = idx;
            } else if (cat == 1) {
                prm.listR[dd * CAP + idx] = gtid;
            } else {
                prm.listHd[dd * CAP + idx] = gtid;
                if (winner) prm.firstH[(size_t)dd * NN + p] = idx;
            }
        }
    }
}

// ---------------------------------------------------------------------------
// setup C: append children to per-slot lists (scattered atomics only)
__global__ __launch_bounds__(256)
void setupC(Prm prm) {
    for (int t = blockIdx.x * 256 + threadIdx.x; t < 12 * CAP; t += gridDim.x * 256) {
        int dd = t / CAP, g = t - dd * CAP;
        int d1 = dd + 1;
        if (g < min(prm.cntB[dd * 3 + 0], CAP)) {            // lefts (tag 0)
            int c = prm.listL[dd * CAP + g];
            int s = prm.firstL[(size_t)dd * NN + prm.parents[c]];
            int idx = atomicAdd(&prm.cntCLR[dd * CAP + s], 1);
            if (idx < CLR) prm.childLR[(size_t)(dd * CAP + s) * CLR + idx] = c * 2;
        }
        if (g < min(prm.cntB[dd * 3 + 1], CAP)) {            // rights (tag 1)
            int c = prm.listR[dd * CAP + g];
            int p = prm.parents[c];
            if ((prm.maskL[p] >> d1) & 1) {                  // only if parent has a left
                int s = prm.firstL[(size_t)dd * NN + p];
                int idx = atomicAdd(&prm.cntCLR[dd * CAP + s], 1);
                if (idx < CLR) prm.childLR[(size_t)(dd * CAP + s) * CLR + idx] = c * 2 + 1;
            }
        }
        if (g < min(prm.cntB[dd * 3 + 2], CAP)) {            // heads: store POSITION g
            int c = prm.listHd[dd * CAP + g];
            int s = prm.firstH[(size_t)dd * NN + prm.parents[c]];
            int idx = atomicAdd(&prm.cntCH[dd * CAP + s], 1);
            if (idx < CH) prm.childH[(size_t)(dd * CAP + s) * CH + idx] = g;
        }
    }
}

// ---------------------------------------------------------------------------
// RR-row 2-layer MLP, 256 threads, split-K halves h=tid>>7, batch-8 weight
// preload, scalar b32 LDS broadcast reads (float4-LDS variant measured SLOWER
// in R18: 785 vs 734 us). Canonical-dup single-writer discipline on x.
template <int MODE, int INDIM>
__device__ void mlpR(const Prm& prm, int d, int g0, int n,
                     const int* __restrict__ rowList,
                     const float* __restrict__ W1, const float* __restrict__ b1,
                     const float* __restrict__ W2, const float* __restrict__ b2,
                     float* sh_raw) {
    const int tid = threadIdx.x;
    const int h = tid >> 7, j = tid & 127;
    float (*sh_in)[INDIM] = (float (*)[INDIM])sh_raw;
    float (*sh_h)[HH]     = (float (*)[HH])(sh_raw + RR * INDIM);
    float (*sh_pt)[HH]    = (float (*)[HH])(sh_raw + RR * INDIM + RR * HH);
    const int dd = d - 1;

    if (MODE == 0) {
        #pragma unroll
        for (int i = 0; i < RR / 2; ++i) {
            int r = h + 2 * i;                      // each half stages 4 rows
            int g = g0 + r;
            float lv = 0.f, rv = 0.f, pv = 0.f;
            if (g < n) {
                int p = prm.parents[rowList[g]];
                int s = prm.firstL[(size_t)dd * NN + p];
                lv = prm.left_c [(size_t)s * HH + j];
                rv = prm.right_c[(size_t)s * HH + j];
                if (j < EE) pv = prm.pef[(size_t)p * EE + j];
            }
            sh_in[r][j] = lv;
            sh_in[r][HH + j] = rv;
            if (j < EE) sh_in[r][2 * HH + j] = pv;
        }
    } else if (MODE == 2) {
        #pragma unroll
        for (int i = 0; i < RR / 2; ++i) {
            int r = h + 2 * i;
            int g = g0 + r;
            float xv = 0.f, mh = 0.f;
            if (g < n) {
                int p = prm.parents[rowList[g]];
                int s = prm.firstH[(size_t)dd * NN + p];
                xv = prm.x[(size_t)p * HH + j];
                int cb = dd * CAP + s;
                int cnt = prm.cntCH[cb];
                if (cnt > CH) cnt = CH;
                for (int i2 = 0; i2 < cnt; ++i2) {
                    int pos = prm.childH[(size_t)cb * CH + i2];
                    mh += prm.lepOut[(size_t)pos * HH + j];
                }
            }
            sh_in[r][j] = xv;
            sh_in[r][HH + j] = mh;
        }
    } else {
        for (int idx = tid; idx < RR * INDIM; idx += 256) {
            int r = idx / INDIM, k = idx - r * INDIM;
            int g = g0 + r;
            float v = 0.f;
            if (g < n) {
                int c = rowList[g];
                if (k < HH) v = prm.x[(size_t)c * HH + k];
                else        v = prm.plef[(size_t)c * EE + (k - HH)];
            }
            sh_in[r][k] = v;
        }
    }
    __syncthreads();

    constexpr int KH1 = INDIM / 2;
    float acc[RR];
    #pragma unroll
    for (int r = 0; r < RR; ++r) acc[r] = 0.f;
    {
        const float* Wp = W1 + (size_t)h * KH1 * HH + j;
        for (int k = 0; k < KH1; k += 8) {
            float wv[8];
            #pragma unroll
            for (int u = 0; u < 8; ++u) wv[u] = Wp[(size_t)(k + u) * HH];
            #pragma unroll
            for (int u = 0; u < 8; ++u) {
                float w = wv[u];
                int kk = h * KH1 + k + u;
                #pragma unroll
                for (int r = 0; r < RR; ++r) acc[r] += sh_in[r][kk] * w;
            }
        }
    }
    if (h == 1) {
        #pragma unroll
        for (int r = 0; r < RR; ++r) sh_pt[r][j] = acc[r];
    }
    __syncthreads();
    if (h == 0) {
        float bb = b1[j];
        #pragma unroll
        for (int r = 0; r < RR; ++r) sh_h[r][j] = fmaxf(acc[r] + sh_pt[r][j] + bb, 0.f);
    }
    __syncthreads();

    float acc2[RR];
    #pragma unroll
    for (int r = 0; r < RR; ++r) acc2[r] = 0.f;
    {
        const float* Wp = W2 + (size_t)h * (HH / 2) * HH + j;
        for (int k = 0; k < HH / 2; k += 8) {
            float wv[8];
            #pragma unroll
            for (int u = 0; u < 8; ++u) wv[u] = Wp[(size_t)(k + u) * HH];
            #pragma unroll
            for (int u = 0; u < 8; ++u) {
                float w = wv[u];
                int kk = h * (HH / 2) + k + u;
                #pragma unroll
                for (int r = 0; r < RR; ++r) acc2[r] += sh_h[r][kk] * w;
            }
        }
    }
    if (h == 1) {
        #pragma unroll
        for (int r = 0; r < RR; ++r) sh_pt[r][j] = acc2[r];
    }
    __syncthreads();
    if (h == 0) {
        float bb2 = b2[j];
        for (int r = 0; r < RR; ++r) {
            int g = g0 + r;
            if (g >= n) break;
            float val = acc2[r] + sh_pt[r][j] + bb2;
            if (MODE == 1) {
                prm.lepOut[(size_t)g * HH + j] = val;
            } else if (MODE == 0) {
                int p = prm.parents[rowList[g]];
                if (g == prm.firstL[(size_t)dd * NN + p])      // canonical dup only
                    prm.x[(size_t)p * HH + j] = val;
            } else {
                int p = prm.parents[rowList[g]];
                if (g == prm.firstH[(size_t)dd * NN + p] &&    // canonical dup only
                    !((prm.maskL[p] >> d) & 1))                // parents_mask priority
                    prm.x[(size_t)p * HH + j] = val;
            }
        }
    }
}

// ---------------------------------------------------------------------------
// S1 (reads x only): gather left/right child sums [0,G_GATHER) || lep MLP rest
__global__ __launch_bounds__(256, 4)
void s1_kernel(Prm prm, int d) {
    const int dd = d - 1;
    const int bid = blockIdx.x, tid = threadIdx.x;
    if (bid < G_GATHER) {
        int nL = min(prm.cntB[dd * 3 + 0], CAP);
        int w = tid >> 5, lane = tid & 31;          // 8 workers x 32 lanes, float4
        for (int s = bid * 8 + w; s < nL; s += G_GATHER * 8) {
            int cb = dd * CAP + s;
            int cnt = prm.cntCLR[cb];
            if (cnt > CLR) cnt = CLR;
            float4 l = make_float4(0.f, 0.f, 0.f, 0.f);
            float4 rt = make_float4(0.f, 0.f, 0.f, 0.f);
            for (int i = 0; i < cnt; ++i) {
                int e = prm.childLR[(size_t)cb * CLR + i];
                const float4 v = *(const float4*)(prm.x + (size_t)(e >> 1) * HH + lane * 4);
                if (e & 1) { rt.x += v.x; rt.y += v.y; rt.z += v.z; rt.w += v.w; }
                else       { l.x  += v.x; l.y  += v.y; l.z  += v.z; l.w  += v.w; }
            }
            *(float4*)(prm.left_c  + (size_t)s * HH + lane * 4) = l;
            *(float4*)(prm.right_c + (size_t)s * HH + lane * 4) = rt;
        }
    } else {
        __shared__ float sh_raw[RR * (HH + EE) + 2 * RR * HH];
        int nH = min(prm.cntB[dd * 3 + 2], CAP);
        int g0 = (bid - G_GATHER) * RR;
        if (g0 < nH)
            mlpR<1, HH + EE>(prm, d, g0, nH, prm.listHd + dd * CAP,
                             prm.pW1, prm.pb1, prm.pW2, prm.pb2, sh_raw);
    }
}

// ---------------------------------------------------------------------------
// S2 (writes x): merger [0,CAP/RR) || lem [CAP/RR, 2*CAP/RR).
// Single-writer per x row (canonical dup only); lem's x-read races only on
// rows whose output is discarded.
__global__ __launch_bounds__(256, 4)
void s2_kernel(Prm prm, int d) {
    const int dd = d - 1;
    const int bid = blockIdx.x;
    __shared__ float sh_raw[RR * (2 * HH + EE) + 2 * RR * HH];
    if (bid < CAP / RR) {
        int nL = min(prm.cntB[dd * 3 + 0], CAP);
        int g0 = bid * RR;
        if (g0 < nL)
            mlpR<0, 2 * HH + EE>(prm, d, g0, nL, prm.listL + dd * CAP,
                                 prm.mW1, prm.mb1, prm.mW2, prm.mb2, sh_raw);
    } else {
        int nH = min(prm.cntB[dd * 3 + 2], CAP);
        int g0 = (bid - CAP / RR) * RR;
        if (g0 < nH)
            mlpR<2, 2 * HH>(prm, d, g0, nH, prm.listHd + dd * CAP,
                            prm.eW1, prm.eb1, prm.eW2, prm.eb2, sh_raw);
    }
}

// ---------------------------------------------------------------------------
extern "C" void kernel_launch(void* const* d_in, const int* in_sizes, int n_in,
                              void* d_out, int out_size, void* d_ws, size_t ws_size,
                              hipStream_t stream) {
    Prm prm;
    prm.x_in    = (const float*)d_in[0];
    const int* edge = (const int*)d_in[1];
    prm.depths  = (const int*)d_in[2];
    prm.states  = (const int*)d_in[3];
    prm.pef     = (const float*)d_in[4];
    prm.plef    = (const float*)d_in[5];
    prm.mW1 = (const float*)d_in[6];  prm.mb1 = (const float*)d_in[7];
    prm.mW2 = (const float*)d_in[8];  prm.mb2 = (const float*)d_in[9];
    prm.pW1 = (const float*)d_in[10]; prm.pb1 = (const float*)d_in[11];
    prm.pW2 = (const float*)d_in[12]; prm.pb2 = (const float*)d_in[13];
    prm.eW1 = (const float*)d_in[14]; prm.eb1 = (const float*)d_in[15];
    prm.eW2 = (const float*)d_in[16]; prm.eb2 = (const float*)d_in[17];
    prm.x = (float*)d_out;
    prm.parents = edge + NN;

    char* w = (char*)d_ws;
    auto alloc = [&](size_t bytes) {
        void* p = (void*)w;
        w += (bytes + 255) & ~(size_t)255;
        return p;
    };
    // ---- zeroed region ----
    char* zbase = w;
    prm.cntB   = (int*)alloc(64 * 4);
    prm.cntCLR = (int*)alloc((size_t)12 * CAP * 4);
    prm.cntCH  = (int*)alloc((size_t)12 * CAP * 4);
    prm.maskL  = (int*)alloc((size_t)NN * 4);
    prm.maskH  = (int*)alloc((size_t)NN * 4);
    size_t zbytes = (size_t)(w - zbase);
    // ---- written by setupA winners (no init needed) ----
    prm.firstL = (int*)alloc((size_t)12 * NN * 4);
    prm.firstH = (int*)alloc((size_t)12 * NN * 4);
    // ---- non-zeroed (fully rebuilt before use each launch) ----
    prm.listL     = (int*)alloc((size_t)12 * CAP * 4);
    prm.listR     = (int*)alloc((size_t)12 * CAP * 4);
    prm.listHd    = (int*)alloc((size_t)12 * CAP * 4);
    prm.childLR   = (int*)alloc((size_t)12 * CAP * CLR * 4);
    prm.childH    = (int*)alloc((size_t)12 * CAP * CH * 4);
    prm.left_c    = (float*)alloc((size_t)CAP * HH * 4);
    prm.right_c   = (float*)alloc((size_t)CAP * HH * 4);
    prm.lepOut    = (float*)alloc((size_t)CAP * HH * 4);

    hipMemsetAsync(zbase, 0, zbytes, stream);

    copy_x<<<4096, 256, 0, stream>>>((const floatx4*)prm.x_in, (floatx4*)prm.x);
    setupA<<<NN / 128, 128, 0, stream>>>(prm);
    setupC<<<384, 256, 0, stream>>>(prm);

    for (int d = MAXD; d >= 1; --d) {
        s1_kernel<<<G_GATHER + CAP / RR, 256, 0, stream>>>(prm, d);
        s2_kernel<<<2 * (CAP / RR), 256, 0, stream>>>(prm, d);
    }
}